// Round 1
// 250.837 us; speedup vs baseline: 1.0082x; 1.0082x over previous
//
#include <hip/hip_runtime.h>
#include <hip/hip_bf16.h>
#include <stdint.h>

#define BSZ 1024
#define KF 32768            // feature length (elements == bytes in fp8)
#define SPLITK 32
#define KPER (KF / SPLITK)  // 1024
#define BKB 128             // K bytes staged per iter
#define NKT (KPER / BKB)    // 8 K-steps per block
#define TEMP_INV 10.0f

typedef float f32x4 __attribute__((ext_vector_type(4)));
typedef int v8i __attribute__((ext_vector_type(8)));

__device__ __forceinline__ void async_copy16(const void* g, void* l) {
    __builtin_amdgcn_global_load_lds(
        (const __attribute__((address_space(1))) void*)g,
        (__attribute__((address_space(3))) void*)l, 16, 0, 0);
}

__device__ __forceinline__ float waveSum(float v) {
    for (int o = 32; o > 0; o >>= 1) v += __shfl_down(v, o);
    return v;
}
__device__ __forceinline__ float waveMax(float v) {
    for (int o = 32; o > 0; o >>= 1) v = fmaxf(v, __shfl_down(v, o));
    return v;
}
__device__ __forceinline__ float blockSum(float v, float* red, int tid) {
    v = waveSum(v);
    __syncthreads();
    if ((tid & 63) == 0) red[tid >> 6] = v;
    __syncthreads();
    return red[0] + red[1] + red[2] + red[3];
}
__device__ __forceinline__ float blockMax(float v, float* red, int tid) {
    v = waveMax(v);
    __syncthreads();
    if ((tid & 63) == 0) red[tid >> 6] = v;
    __syncthreads();
    return fmaxf(fmaxf(red[0], red[1]), fmaxf(red[2], red[3]));
}

// K1: per-row sum of squares (fp32, exact) + fp32->fp8(e4m3) convert.
__global__ __launch_bounds__(256) void k_norm_convert(
    const float* __restrict__ f, unsigned char* __restrict__ f8,
    float* __restrict__ inv_norm) {
    int row = blockIdx.x, tid = threadIdx.x;
    const float4* src = (const float4*)(f + (size_t)row * KF);
    int4* dst = (int4*)(f8 + (size_t)row * KF);
    float ss = 0.f;
    for (int o = 0; o < 8; ++o) {
        int base4 = o * 1024 + tid * 4;
        int4 pk;
        int* pkp = &pk.x;
#pragma unroll
        for (int q = 0; q < 4; ++q) {
            float4 v = src[base4 + q];
            ss += v.x * v.x + v.y * v.y + v.z * v.z + v.w * v.w;
            int wd = __builtin_amdgcn_cvt_pk_fp8_f32(v.x, v.y, 0, false);
            wd = __builtin_amdgcn_cvt_pk_fp8_f32(v.z, v.w, wd, true);
            pkp[q] = wd;
        }
        dst[o * 256 + tid] = pk;
    }
    __shared__ float red[4];
    float tot = blockSum(ss, red, tid);
    if (tid == 0) inv_norm[row] = 1.0f / fmaxf(sqrtf(tot), 1e-8f);
}

// K2: MX-fp8 (unit scales) gram partials, symmetric tiles (bi>=bj), mirrored
// epilogue. v2: double-buffered LDS + raw s_barrier + explicit waitcnt so the
// next K-step's global_load_lds overlaps this step's ds_read+MFMA (T3-minimum
// 2-phase schedule; the old __syncthreads pair forced a vmcnt(0) drain that
// serialized staging against compute every K-step).
__global__ __launch_bounds__(256) void k_gemm(
    const unsigned char* __restrict__ f8, unsigned char* __restrict__ partials) {
    __shared__ unsigned char Alds[2][128 * BKB];   // 2 x 16 KB
    __shared__ unsigned char Blds[2][128 * BKB];   // 2 x 16 KB  (total 64 KB -> 2 blocks/CU)
    int tid = threadIdx.x;

    int t = blockIdx.x;                 // triangular tile: bi >= bj
    int bi = 0, accu = 0;
    while (accu + bi + 1 <= t) { accu += bi + 1; ++bi; }
    int bj = t - accu;
    int row0 = bi * 128, col0 = bj * 128;
    int p = blockIdx.y;
    size_t kbase = (size_t)p * KPER;

    const unsigned char* Ag = f8 + (size_t)row0 * KF;
    const unsigned char* Bg = f8 + (size_t)col0 * KF;
    int lane = tid & 63, w = tid >> 6;
    int wrow = (w >> 1) * 64, wcol = (w & 1) * 64;
    int mrow = lane & 15, quad = lane >> 4;

    // staging: 1024 chunks of 16B per matrix; LDS slot s of row r holds
    // global chunk s^(r&7)  (XOR swizzle -> 2-way banks on read = free)
    int r_st[4], g_st[4];
#pragma unroll
    for (int c = 0; c < 4; ++c) {
        int idx = c * 256 + tid;
        r_st[c] = idx >> 3;
        g_st[c] = (idx & 7) ^ (r_st[c] & 7);
    }

    f32x4 acc[4][4] = {};

    // prologue: stage kt=0 into buffer 0, wait own copies, barrier
#pragma unroll
    for (int c = 0; c < 4; ++c) {
        int idx = c * 256 + tid;
        async_copy16(Ag + (size_t)r_st[c] * KF + kbase + g_st[c] * 16, &Alds[0][idx * 16]);
        async_copy16(Bg + (size_t)r_st[c] * KF + kbase + g_st[c] * 16, &Blds[0][idx * 16]);
    }
    asm volatile("s_waitcnt vmcnt(0)" ::: "memory");
    __builtin_amdgcn_s_barrier();

#pragma unroll
    for (int kt = 0; kt < NKT; ++kt) {
        int cur = kt & 1;
        // issue next K-step's staging first -> in flight during ds_read+MFMA
        if (kt + 1 < NKT) {
            size_t k0 = kbase + (size_t)(kt + 1) * BKB;
#pragma unroll
            for (int c = 0; c < 4; ++c) {
                int idx = c * 256 + tid;
                async_copy16(Ag + (size_t)r_st[c] * KF + k0 + g_st[c] * 16,
                             &Alds[cur ^ 1][idx * 16]);
                async_copy16(Bg + (size_t)r_st[c] * KF + k0 + g_st[c] * 16,
                             &Blds[cur ^ 1][idx * 16]);
            }
        }
        // fragments: lane covers k = quad*32..quad*32+32 (chunks 2q, 2q+1);
        // identical k-mapping on A and B => gram correct under any shared perm.
        v8i a8[4], b8[4];
#pragma unroll
        for (int mi = 0; mi < 4; ++mi) {
            int rA = wrow + mi * 16 + mrow;
            int4 lo = *(const int4*)&Alds[cur][rA * BKB + ((quad * 2)     ^ (rA & 7)) * 16];
            int4 hi = *(const int4*)&Alds[cur][rA * BKB + ((quad * 2 + 1) ^ (rA & 7)) * 16];
            a8[mi] = (v8i){lo.x, lo.y, lo.z, lo.w, hi.x, hi.y, hi.z, hi.w};
        }
#pragma unroll
        for (int ni = 0; ni < 4; ++ni) {
            int rB = wcol + ni * 16 + mrow;
            int4 lo = *(const int4*)&Blds[cur][rB * BKB + ((quad * 2)     ^ (rB & 7)) * 16];
            int4 hi = *(const int4*)&Blds[cur][rB * BKB + ((quad * 2 + 1) ^ (rB & 7)) * 16];
            b8[ni] = (v8i){lo.x, lo.y, lo.z, lo.w, hi.x, hi.y, hi.z, hi.w};
        }
#pragma unroll
        for (int mi = 0; mi < 4; ++mi)
#pragma unroll
            for (int ni = 0; ni < 4; ++ni)
                acc[mi][ni] = __builtin_amdgcn_mfma_scale_f32_16x16x128_f8f6f4(
                    a8[mi], b8[ni], acc[mi][ni],
                    0, 0,                     // cbsz/blgp = fp8(e4m3)
                    0, 0x7F7F7F7F,            // A scales: E8M0 127 -> 2^0 (exact)
                    0, 0x7F7F7F7F);           // B scales: unit
        // per-wave wait BEFORE barrier (counters are per-wave):
        //   vmcnt(0): my stage copies for kt+1 have landed in LDS
        //   lgkmcnt(0): my ds_reads of buf[cur] drained (next iter overwrites it)
        asm volatile("s_waitcnt vmcnt(0) lgkmcnt(0)" ::: "memory");
        __builtin_amdgcn_s_barrier();
    }

    unsigned char* outp = partials + (size_t)p * BSZ * BSZ;
#pragma unroll
    for (int mi = 0; mi < 4; ++mi)
#pragma unroll
        for (int ni = 0; ni < 4; ++ni)
#pragma unroll
            for (int r = 0; r < 4; ++r) {
                int row = row0 + wrow + mi * 16 + quad * 4 + r;   // C/D: row=(lane>>4)*4+reg
                int col = col0 + wcol + ni * 16 + mrow;           //      col=lane&15
                int b = __builtin_amdgcn_cvt_pk_fp8_f32(
                            acc[mi][ni][r], acc[mi][ni][r], 0, false);
                outp[(size_t)row * BSZ + col] = (unsigned char)(b & 0xFF);
            }
    if (bi != bj) {
#pragma unroll
        for (int mi = 0; mi < 4; ++mi)
#pragma unroll
            for (int ni = 0; ni < 4; ++ni) {
                int rowm = col0 + wcol + ni * 16 + mrow;
                int colm = row0 + wrow + mi * 16 + quad * 4;   // 4-aligned
                int pk = __builtin_amdgcn_cvt_pk_fp8_f32(
                             acc[mi][ni][0], acc[mi][ni][1], 0, false);
                pk = __builtin_amdgcn_cvt_pk_fp8_f32(
                         acc[mi][ni][2], acc[mi][ni][3], pk, true);
                *(int*)&outp[(size_t)rowm * BSZ + colm] = pk;
            }
    }
}

// K3: per-row loss, single pass. Scores <= 10 analytically (cosine/T), so use
// constant shift 10 (loss is shift-invariant); no srow LDS staging.
__global__ __launch_bounds__(256) void k_loss_rows(
    const unsigned char* __restrict__ partials, const float* __restrict__ inv_norm,
    const int* __restrict__ labels, float* __restrict__ rloss,
    float* __restrict__ rvalid, float* __restrict__ rcorr) {
    int i = blockIdx.x, tid = threadIdx.x;
    __shared__ float red[4];
    float inv_i = inv_norm[i];
    int lab_i = labels[i];

    int j4 = tid * 4;
    float sx = 0.f, sy = 0.f, sz = 0.f, sw = 0.f;
#pragma unroll
    for (int p2 = 0; p2 < SPLITK; ++p2) {
        int v = *(const int*)&partials[(size_t)p2 * BSZ * BSZ + (size_t)i * BSZ + j4];
        sx += __builtin_amdgcn_cvt_f32_fp8(v, 0);
        sy += __builtin_amdgcn_cvt_f32_fp8(v, 1);
        sz += __builtin_amdgcn_cvt_f32_fp8(v, 2);
        sw += __builtin_amdgcn_cvt_f32_fp8(v, 3);
    }
    float4 invj = *(const float4*)&inv_norm[j4];
    float s4[4];
    s4[0] = sx * inv_i * invj.x * TEMP_INV;
    s4[1] = sy * inv_i * invj.y * TEMP_INV;
    s4[2] = sz * inv_i * invj.z * TEMP_INV;
    s4[3] = sw * inv_i * invj.w * TEMP_INV;
    int4 labj = *(const int4*)&labels[j4];
    const int* labjp = &labj.x;

    float pos_sum = 0.f, neg_sum = 0.f, mp = -3.0e38f, mn = -3.0e38f;
#pragma unroll
    for (int q = 0; q < 4; ++q) {
        int j = j4 + q;
        if (j == i) continue;
        float s = s4[q];
        float e = __expf(s - 10.0f);           // s <= 10+eps -> e in (0,~1]
        if (labjp[q] == lab_i) { pos_sum += e; mp = fmaxf(mp, s); }
        else                   { neg_sum += e; mn = fmaxf(mn, s); }
    }
    float ps = blockSum(pos_sum, red, tid);
    float ns = blockSum(neg_sum, red, tid);
    float mpa = blockMax(mp, red, tid);
    float mna = blockMax(mn, red, tid);
    if (tid == 0) {
        bool valid = (mpa > -1.0e37f) && (mna > -1.0e37f);
        rloss[i]  = valid ? (logf(ns) - logf(ps)) : 0.f;
        rvalid[i] = valid ? 1.f : 0.f;
        rcorr[i]  = (valid && (mpa > mna)) ? 1.f : 0.f;
    }
}

// K4: final scalar reduce -> d_out[0]=loss, d_out[1]=accuracy
__global__ __launch_bounds__(256) void k_final(
    const float* __restrict__ rloss, const float* __restrict__ rvalid,
    const float* __restrict__ rcorr, float* __restrict__ out) {
    __shared__ float red[4];
    int tid = threadIdx.x;
    float sl = 0.f, sv = 0.f, sc = 0.f;
    for (int c = 0; c < 4; ++c) {
        int j = c * 256 + tid;
        sl += rloss[j]; sv += rvalid[j]; sc += rcorr[j];
    }
    sl = blockSum(sl, red, tid);
    sv = blockSum(sv, red, tid);
    sc = blockSum(sc, red, tid);
    if (tid == 0) {
        out[0] = (sv > 0.f) ? sl / fmaxf(sv, 1.f) : 0.f;
        out[1] = (sv > 0.f) ? sc / fmaxf(sv, 1.f) : 0.5f;
    }
}

extern "C" void kernel_launch(void* const* d_in, const int* in_sizes, int n_in,
                              void* d_out, int out_size, void* d_ws, size_t ws_size,
                              hipStream_t stream) {
    const float* feats = (const float*)d_in[0];
    const int* labels = (const int*)d_in[1];
    float* out = (float*)d_out;
    char* ws = (char*)d_ws;

    // ws: [0,32MB) fp8 features | [32MB,64MB) 32 fp8 gram partials | small arrays
    unsigned char* f8       = (unsigned char*)ws;
    unsigned char* partials = (unsigned char*)(ws + (size_t)32 * 1024 * 1024);
    float* inv_norm         = (float*)(ws + (size_t)64 * 1024 * 1024);
    float* rloss            = inv_norm + BSZ;
    float* rvalid           = rloss + BSZ;
    float* rcorr            = rvalid + BSZ;

    k_norm_convert<<<BSZ, 256, 0, stream>>>(feats, f8, inv_norm);
    k_gemm<<<dim3(36, SPLITK), 256, 0, stream>>>(f8, partials);
    k_loss_rows<<<BSZ, 256, 0, stream>>>(partials, inv_norm, labels, rloss, rvalid, rcorr);
    k_final<<<1, 256, 0, stream>>>(rloss, rvalid, rcorr, out);
}

// Round 2
// 241.597 us; speedup vs baseline: 1.0468x; 1.0382x over previous
//
#include <hip/hip_runtime.h>
#include <hip/hip_bf16.h>
#include <stdint.h>

#define BSZ 1024
#define KF 32768            // feature length (elements == bytes in fp8)
#define SPLITK 32
#define KPER (KF / SPLITK)  // 1024
#define BKB 128             // K bytes staged per iter
#define TEMP_INV 10.0f

typedef float f32x4 __attribute__((ext_vector_type(4)));
typedef int v8i __attribute__((ext_vector_type(8)));

__device__ __forceinline__ void async_copy16(const void* g, void* l) {
    __builtin_amdgcn_global_load_lds(
        (const __attribute__((address_space(1))) void*)g,
        (__attribute__((address_space(3))) void*)l, 16, 0, 0);
}

__device__ __forceinline__ float waveSum(float v) {
    for (int o = 32; o > 0; o >>= 1) v += __shfl_down(v, o);
    return v;
}
__device__ __forceinline__ float waveMax(float v) {
    for (int o = 32; o > 0; o >>= 1) v = fmaxf(v, __shfl_down(v, o));
    return v;
}
__device__ __forceinline__ float blockSum(float v, float* red, int tid) {
    v = waveSum(v);
    __syncthreads();
    if ((tid & 63) == 0) red[tid >> 6] = v;
    __syncthreads();
    return red[0] + red[1] + red[2] + red[3];
}
__device__ __forceinline__ float blockMax(float v, float* red, int tid) {
    v = waveMax(v);
    __syncthreads();
    if ((tid & 63) == 0) red[tid >> 6] = v;
    __syncthreads();
    return fmaxf(fmaxf(red[0], red[1]), fmaxf(red[2], red[3]));
}

// K1: per-row sum of squares (fp32, exact) + fp32->fp8(e4m3) convert.
__global__ __launch_bounds__(256) void k_norm_convert(
    const float* __restrict__ f, unsigned char* __restrict__ f8,
    float* __restrict__ inv_norm) {
    int row = blockIdx.x, tid = threadIdx.x;
    const float4* src = (const float4*)(f + (size_t)row * KF);
    int4* dst = (int4*)(f8 + (size_t)row * KF);
    float ss = 0.f;
    for (int o = 0; o < 8; ++o) {
        int base4 = o * 1024 + tid * 4;
        int4 pk;
        int* pkp = &pk.x;
#pragma unroll
        for (int q = 0; q < 4; ++q) {
            float4 v = src[base4 + q];
            ss += v.x * v.x + v.y * v.y + v.z * v.z + v.w * v.w;
            int wd = __builtin_amdgcn_cvt_pk_fp8_f32(v.x, v.y, 0, false);
            wd = __builtin_amdgcn_cvt_pk_fp8_f32(v.z, v.w, wd, true);
            pkp[q] = wd;
        }
        dst[o * 256 + tid] = pk;
    }
    __shared__ float red[4];
    float tot = blockSum(ss, red, tid);
    if (tid == 0) inv_norm[row] = 1.0f / fmaxf(sqrtf(tot), 1e-8f);
}

// K2: MX-fp8 (unit scales) gram partials, symmetric tiles (bi>=bj), mirrored
// epilogue. v3: back to single-buffer 32KB LDS (5 blocks/CU -> full residency,
// no tail quantization; R1's 64KB dbuf halved TLP for no net gain) PLUS
// XCD-aware block decode: HW assigns XCD = linear_bid % 8, so we map 4
// consecutive split-K slices p to each XCD. One p-slice of f8 = 1024 rows x
// 1KB = 1MB; 4 slices = 4MB = exactly one XCD's L2. Every A/B staging panel
// is a subset of the block's p-slice -> ~270MB of the 302MB staging traffic
// becomes L2 hits instead of L3 reads.
__global__ __launch_bounds__(256) void k_gemm(
    const unsigned char* __restrict__ f8, unsigned char* __restrict__ partials) {
    __shared__ unsigned char Alds[128 * BKB];   // 16 KB
    __shared__ unsigned char Blds[128 * BKB];   // 16 KB
    int tid = threadIdx.x;

    // XCD-aware decode: bid -> (g = XCD slot, p = split-K slice, t = tri tile)
    // g = bid % 8 (HW round-robin), p in [4g, 4g+4), t in [0,36). Bijective.
    int bid = blockIdx.x;
    int g = bid & 7;
    int j = bid >> 3;                  // 0..143
    int p = (g << 2) + (j / 36);       // 0..31
    int t = j % 36;                    // triangular tile id

    int bi = 0, accu = 0;
    while (accu + bi + 1 <= t) { accu += bi + 1; ++bi; }
    int bj = t - accu;
    int row0 = bi * 128, col0 = bj * 128;
    size_t kbase = (size_t)p * KPER;

    const unsigned char* Ag = f8 + (size_t)row0 * KF;
    const unsigned char* Bg = f8 + (size_t)col0 * KF;
    int lane = tid & 63, w = tid >> 6;
    int wrow = (w >> 1) * 64, wcol = (w & 1) * 64;
    int mrow = lane & 15, quad = lane >> 4;

    // staging: 1024 chunks of 16B per matrix; LDS slot s of row r holds
    // global chunk s^(r&7)  (XOR swizzle -> 2-way banks on read = free)
    int r_st[4], g_st[4];
#pragma unroll
    for (int c = 0; c < 4; ++c) {
        int idx = c * 256 + tid;
        r_st[c] = idx >> 3;
        g_st[c] = (idx & 7) ^ (r_st[c] & 7);
    }

    f32x4 acc[4][4] = {};

    for (int kt = 0; kt < KPER / BKB; ++kt) {   // 8 iters
        size_t k0 = kbase + (size_t)kt * BKB;
        __syncthreads();
#pragma unroll
        for (int c = 0; c < 4; ++c) {
            int idx = c * 256 + tid;
            async_copy16(Ag + (size_t)r_st[c] * KF + k0 + g_st[c] * 16, &Alds[idx * 16]);
            async_copy16(Bg + (size_t)r_st[c] * KF + k0 + g_st[c] * 16, &Blds[idx * 16]);
        }
        __syncthreads();
        // fragments: lane covers k = quad*32..quad*32+32 (chunks 2q, 2q+1);
        // identical k-mapping on A and B => gram correct under any shared perm.
        v8i a8[4], b8[4];
#pragma unroll
        for (int mi = 0; mi < 4; ++mi) {
            int rA = wrow + mi * 16 + mrow;
            int4 lo = *(const int4*)&Alds[rA * BKB + ((quad * 2)     ^ (rA & 7)) * 16];
            int4 hi = *(const int4*)&Alds[rA * BKB + ((quad * 2 + 1) ^ (rA & 7)) * 16];
            a8[mi] = (v8i){lo.x, lo.y, lo.z, lo.w, hi.x, hi.y, hi.z, hi.w};
        }
#pragma unroll
        for (int ni = 0; ni < 4; ++ni) {
            int rB = wcol + ni * 16 + mrow;
            int4 lo = *(const int4*)&Blds[rB * BKB + ((quad * 2)     ^ (rB & 7)) * 16];
            int4 hi = *(const int4*)&Blds[rB * BKB + ((quad * 2 + 1) ^ (rB & 7)) * 16];
            b8[ni] = (v8i){lo.x, lo.y, lo.z, lo.w, hi.x, hi.y, hi.z, hi.w};
        }
#pragma unroll
        for (int mi = 0; mi < 4; ++mi)
#pragma unroll
            for (int ni = 0; ni < 4; ++ni)
                acc[mi][ni] = __builtin_amdgcn_mfma_scale_f32_16x16x128_f8f6f4(
                    a8[mi], b8[ni], acc[mi][ni],
                    0, 0,                     // cbsz/blgp = fp8(e4m3)
                    0, 0x7F7F7F7F,            // A scales: E8M0 127 -> 2^0 (exact)
                    0, 0x7F7F7F7F);           // B scales: unit
    }

    unsigned char* outp = partials + (size_t)p * BSZ * BSZ;
#pragma unroll
    for (int mi = 0; mi < 4; ++mi)
#pragma unroll
        for (int ni = 0; ni < 4; ++ni)
#pragma unroll
            for (int r = 0; r < 4; ++r) {
                int row = row0 + wrow + mi * 16 + quad * 4 + r;   // C/D: row=(lane>>4)*4+reg
                int col = col0 + wcol + ni * 16 + mrow;           //      col=lane&15
                int b = __builtin_amdgcn_cvt_pk_fp8_f32(
                            acc[mi][ni][r], acc[mi][ni][r], 0, false);
                outp[(size_t)row * BSZ + col] = (unsigned char)(b & 0xFF);
            }
    if (bi != bj) {
#pragma unroll
        for (int mi = 0; mi < 4; ++mi)
#pragma unroll
            for (int ni = 0; ni < 4; ++ni) {
                int rowm = col0 + wcol + ni * 16 + mrow;
                int colm = row0 + wrow + mi * 16 + quad * 4;   // 4-aligned
                int pk = __builtin_amdgcn_cvt_pk_fp8_f32(
                             acc[mi][ni][0], acc[mi][ni][1], 0, false);
                pk = __builtin_amdgcn_cvt_pk_fp8_f32(
                         acc[mi][ni][2], acc[mi][ni][3], pk, true);
                *(int*)&outp[(size_t)rowm * BSZ + colm] = pk;
            }
    }
}

// K3: per-row loss, single pass. Scores <= 10 analytically (cosine/T), so use
// constant shift 10 (loss is shift-invariant); no srow LDS staging.
__global__ __launch_bounds__(256) void k_loss_rows(
    const unsigned char* __restrict__ partials, const float* __restrict__ inv_norm,
    const int* __restrict__ labels, float* __restrict__ rloss,
    float* __restrict__ rvalid, float* __restrict__ rcorr) {
    int i = blockIdx.x, tid = threadIdx.x;
    __shared__ float red[4];
    float inv_i = inv_norm[i];
    int lab_i = labels[i];

    int j4 = tid * 4;
    float sx = 0.f, sy = 0.f, sz = 0.f, sw = 0.f;
#pragma unroll
    for (int p2 = 0; p2 < SPLITK; ++p2) {
        int v = *(const int*)&partials[(size_t)p2 * BSZ * BSZ + (size_t)i * BSZ + j4];
        sx += __builtin_amdgcn_cvt_f32_fp8(v, 0);
        sy += __builtin_amdgcn_cvt_f32_fp8(v, 1);
        sz += __builtin_amdgcn_cvt_f32_fp8(v, 2);
        sw += __builtin_amdgcn_cvt_f32_fp8(v, 3);
    }
    float4 invj = *(const float4*)&inv_norm[j4];
    float s4[4];
    s4[0] = sx * inv_i * invj.x * TEMP_INV;
    s4[1] = sy * inv_i * invj.y * TEMP_INV;
    s4[2] = sz * inv_i * invj.z * TEMP_INV;
    s4[3] = sw * inv_i * invj.w * TEMP_INV;
    int4 labj = *(const int4*)&labels[j4];
    const int* labjp = &labj.x;

    float pos_sum = 0.f, neg_sum = 0.f, mp = -3.0e38f, mn = -3.0e38f;
#pragma unroll
    for (int q = 0; q < 4; ++q) {
        int j = j4 + q;
        if (j == i) continue;
        float s = s4[q];
        float e = __expf(s - 10.0f);           // s <= 10+eps -> e in (0,~1]
        if (labjp[q] == lab_i) { pos_sum += e; mp = fmaxf(mp, s); }
        else                   { neg_sum += e; mn = fmaxf(mn, s); }
    }
    float ps = blockSum(pos_sum, red, tid);
    float ns = blockSum(neg_sum, red, tid);
    float mpa = blockMax(mp, red, tid);
    float mna = blockMax(mn, red, tid);
    if (tid == 0) {
        bool valid = (mpa > -1.0e37f) && (mna > -1.0e37f);
        rloss[i]  = valid ? (logf(ns) - logf(ps)) : 0.f;
        rvalid[i] = valid ? 1.f : 0.f;
        rcorr[i]  = (valid && (mpa > mna)) ? 1.f : 0.f;
    }
}

// K4: final scalar reduce -> d_out[0]=loss, d_out[1]=accuracy
__global__ __launch_bounds__(256) void k_final(
    const float* __restrict__ rloss, const float* __restrict__ rvalid,
    const float* __restrict__ rcorr, float* __restrict__ out) {
    __shared__ float red[4];
    int tid = threadIdx.x;
    float sl = 0.f, sv = 0.f, sc = 0.f;
    for (int c = 0; c < 4; ++c) {
        int j = c * 256 + tid;
        sl += rloss[j]; sv += rvalid[j]; sc += rcorr[j];
    }
    sl = blockSum(sl, red, tid);
    sv = blockSum(sv, red, tid);
    sc = blockSum(sc, red, tid);
    if (tid == 0) {
        out[0] = (sv > 0.f) ? sl / fmaxf(sv, 1.f) : 0.f;
        out[1] = (sv > 0.f) ? sc / fmaxf(sv, 1.f) : 0.5f;
    }
}

extern "C" void kernel_launch(void* const* d_in, const int* in_sizes, int n_in,
                              void* d_out, int out_size, void* d_ws, size_t ws_size,
                              hipStream_t stream) {
    const float* feats = (const float*)d_in[0];
    const int* labels = (const int*)d_in[1];
    float* out = (float*)d_out;
    char* ws = (char*)d_ws;

    // ws: [0,32MB) fp8 features | [32MB,64MB) 32 fp8 gram partials | small arrays
    unsigned char* f8       = (unsigned char*)ws;
    unsigned char* partials = (unsigned char*)(ws + (size_t)32 * 1024 * 1024);
    float* inv_norm         = (float*)(ws + (size_t)64 * 1024 * 1024);
    float* rloss            = inv_norm + BSZ;
    float* rvalid           = rloss + BSZ;
    float* rcorr            = rvalid + BSZ;

    k_norm_convert<<<BSZ, 256, 0, stream>>>(feats, f8, inv_norm);
    k_gemm<<<dim3(36 * SPLITK), 256, 0, stream>>>(f8, partials);
    k_loss_rows<<<BSZ, 256, 0, stream>>>(partials, inv_norm, labels, rloss, rvalid, rcorr);
    k_final<<<1, 256, 0, stream>>>(rloss, rvalid, rcorr, out);
}

// Round 3
// 236.442 us; speedup vs baseline: 1.0696x; 1.0218x over previous
//
#include <hip/hip_runtime.h>
#include <hip/hip_bf16.h>
#include <stdint.h>

#define BSZ 1024
#define KF 32768            // feature length (elements == bytes in fp8)
#define SPLITK 16
#define KPER (KF / SPLITK)  // 2048
#define BKB 128             // K bytes staged per iter
#define NKT (KPER / BKB)    // 16 K-steps per block
#define TEMP_INV 10.0f

typedef float f32x4 __attribute__((ext_vector_type(4)));
typedef int v8i __attribute__((ext_vector_type(8)));

__device__ __forceinline__ void async_copy16(const void* g, void* l) {
    __builtin_amdgcn_global_load_lds(
        (const __attribute__((address_space(1))) void*)g,
        (__attribute__((address_space(3))) void*)l, 16, 0, 0);
}

__device__ __forceinline__ float waveSum(float v) {
    for (int o = 32; o > 0; o >>= 1) v += __shfl_down(v, o);
    return v;
}
__device__ __forceinline__ float waveMax(float v) {
    for (int o = 32; o > 0; o >>= 1) v = fmaxf(v, __shfl_down(v, o));
    return v;
}
__device__ __forceinline__ float blockSum(float v, float* red, int tid) {
    v = waveSum(v);
    __syncthreads();
    if ((tid & 63) == 0) red[tid >> 6] = v;
    __syncthreads();
    return red[0] + red[1] + red[2] + red[3];
}
__device__ __forceinline__ float blockMax(float v, float* red, int tid) {
    v = waveMax(v);
    __syncthreads();
    if ((tid & 63) == 0) red[tid >> 6] = v;
    __syncthreads();
    return fmaxf(fmaxf(red[0], red[1]), fmaxf(red[2], red[3]));
}

// K1: per-row sum of squares (fp32, exact) + fp32->fp8(e4m3) convert.
__global__ __launch_bounds__(256) void k_norm_convert(
    const float* __restrict__ f, unsigned char* __restrict__ f8,
    float* __restrict__ inv_norm) {
    int row = blockIdx.x, tid = threadIdx.x;
    const float4* src = (const float4*)(f + (size_t)row * KF);
    int4* dst = (int4*)(f8 + (size_t)row * KF);
    float ss = 0.f;
    for (int o = 0; o < 8; ++o) {
        int base4 = o * 1024 + tid * 4;
        int4 pk;
        int* pkp = &pk.x;
#pragma unroll
        for (int q = 0; q < 4; ++q) {
            float4 v = src[base4 + q];
            ss += v.x * v.x + v.y * v.y + v.z * v.z + v.w * v.w;
            int wd = __builtin_amdgcn_cvt_pk_fp8_f32(v.x, v.y, 0, false);
            wd = __builtin_amdgcn_cvt_pk_fp8_f32(v.z, v.w, wd, true);
            pkp[q] = wd;
        }
        dst[o * 256 + tid] = pk;
    }
    __shared__ float red[4];
    float tot = blockSum(ss, red, tid);
    if (tid == 0) inv_norm[row] = 1.0f / fmaxf(sqrtf(tot), 1e-8f);
}

// K2 v4: SPLITK=16 (16 K-steps/block -> prologue/epilogue amortized 2x,
// partials halved) + double-buffered counted-wait pipeline (prefetch t+1
// hides L2 latency under step t's ds_read+MFMA; ONE barrier per step) +
// T5 setprio around the MFMA cluster (dbuf gives wave role-diversity) +
// XCD-aware decode (2 p-slices per XCD = 2MB working set in 4MB L2).
__global__ __launch_bounds__(256) void k_gemm(
    const unsigned char* __restrict__ f8, unsigned char* __restrict__ partials) {
    __shared__ unsigned char Alds[2][128 * BKB];   // 2 x 16 KB
    __shared__ unsigned char Blds[2][128 * BKB];   // 2 x 16 KB (64 KB -> 2 blocks/CU)
    int tid = threadIdx.x;

    // bid -> (g = XCD = bid%8, p = split-K slice, t = triangular tile). Bijective:
    // j = bid>>3 in [0,72); p = 2g + j/36 in [0,16); t = j%36.
    int bid = blockIdx.x;
    int g = bid & 7;
    int j = bid >> 3;
    int p = (g << 1) + (j / 36);
    int t = j % 36;

    int bi = 0, accu = 0;
    while (accu + bi + 1 <= t) { accu += bi + 1; ++bi; }
    int bj = t - accu;
    int row0 = bi * 128, col0 = bj * 128;
    size_t kbase = (size_t)p * KPER;

    const unsigned char* Ag = f8 + (size_t)row0 * KF;
    const unsigned char* Bg = f8 + (size_t)col0 * KF;
    int lane = tid & 63, w = tid >> 6;
    int wrow = (w >> 1) * 64, wcol = (w & 1) * 64;
    int mrow = lane & 15, quad = lane >> 4;

    // staging: 1024 chunks of 16B per matrix; LDS slot s of row r holds
    // global chunk s^(r&7)  (XOR swizzle -> 2-way banks on read = free)
    int r_st[4], g_st[4];
#pragma unroll
    for (int c = 0; c < 4; ++c) {
        int idx = c * 256 + tid;
        r_st[c] = idx >> 3;
        g_st[c] = (idx & 7) ^ (r_st[c] & 7);
    }

    f32x4 acc[4][4] = {};

    // prologue: stage kt=0 into buffer 0, wait own copies, barrier
#pragma unroll
    for (int c = 0; c < 4; ++c) {
        int idx = c * 256 + tid;
        async_copy16(Ag + (size_t)r_st[c] * KF + kbase + g_st[c] * 16, &Alds[0][idx * 16]);
        async_copy16(Bg + (size_t)r_st[c] * KF + kbase + g_st[c] * 16, &Blds[0][idx * 16]);
    }
    asm volatile("s_waitcnt vmcnt(0)" ::: "memory");
    __builtin_amdgcn_s_barrier();

#pragma unroll
    for (int kt = 0; kt < NKT; ++kt) {
        int cur = kt & 1;
        // issue next K-step's staging first -> in flight during ds_read+MFMA
        if (kt + 1 < NKT) {
            size_t k0 = kbase + (size_t)(kt + 1) * BKB;
#pragma unroll
            for (int c = 0; c < 4; ++c) {
                int idx = c * 256 + tid;
                async_copy16(Ag + (size_t)r_st[c] * KF + k0 + g_st[c] * 16,
                             &Alds[cur ^ 1][idx * 16]);
                async_copy16(Bg + (size_t)r_st[c] * KF + k0 + g_st[c] * 16,
                             &Blds[cur ^ 1][idx * 16]);
            }
        }
        // fragments: lane covers k = quad*32..quad*32+32 (chunks 2q, 2q+1);
        // identical k-mapping on A and B => gram correct under any shared perm.
        v8i a8[4], b8[4];
#pragma unroll
        for (int mi = 0; mi < 4; ++mi) {
            int rA = wrow + mi * 16 + mrow;
            int4 lo = *(const int4*)&Alds[cur][rA * BKB + ((quad * 2)     ^ (rA & 7)) * 16];
            int4 hi = *(const int4*)&Alds[cur][rA * BKB + ((quad * 2 + 1) ^ (rA & 7)) * 16];
            a8[mi] = (v8i){lo.x, lo.y, lo.z, lo.w, hi.x, hi.y, hi.z, hi.w};
        }
#pragma unroll
        for (int ni = 0; ni < 4; ++ni) {
            int rB = wcol + ni * 16 + mrow;
            int4 lo = *(const int4*)&Blds[cur][rB * BKB + ((quad * 2)     ^ (rB & 7)) * 16];
            int4 hi = *(const int4*)&Blds[cur][rB * BKB + ((quad * 2 + 1) ^ (rB & 7)) * 16];
            b8[ni] = (v8i){lo.x, lo.y, lo.z, lo.w, hi.x, hi.y, hi.z, hi.w};
        }
        __builtin_amdgcn_s_setprio(1);
#pragma unroll
        for (int mi = 0; mi < 4; ++mi)
#pragma unroll
            for (int ni = 0; ni < 4; ++ni)
                acc[mi][ni] = __builtin_amdgcn_mfma_scale_f32_16x16x128_f8f6f4(
                    a8[mi], b8[ni], acc[mi][ni],
                    0, 0,                     // cbsz/blgp = fp8(e4m3)
                    0, 0x7F7F7F7F,            // A scales: E8M0 127 -> 2^0 (exact)
                    0, 0x7F7F7F7F);           // B scales: unit
        __builtin_amdgcn_s_setprio(0);
        // per-wave wait BEFORE barrier (counters are per-wave):
        //   vmcnt(0): my stage copies for kt+1 have landed in LDS
        //   lgkmcnt(0): my ds_reads of buf[cur] drained (next iter overwrites it)
        asm volatile("s_waitcnt vmcnt(0) lgkmcnt(0)" ::: "memory");
        __builtin_amdgcn_s_barrier();
    }

    unsigned char* outp = partials + (size_t)p * BSZ * BSZ;
#pragma unroll
    for (int mi = 0; mi < 4; ++mi)
#pragma unroll
        for (int ni = 0; ni < 4; ++ni)
#pragma unroll
            for (int r = 0; r < 4; ++r) {
                int row = row0 + wrow + mi * 16 + quad * 4 + r;   // C/D: row=(lane>>4)*4+reg
                int col = col0 + wcol + ni * 16 + mrow;           //      col=lane&15
                int b = __builtin_amdgcn_cvt_pk_fp8_f32(
                            acc[mi][ni][r], acc[mi][ni][r], 0, false);
                outp[(size_t)row * BSZ + col] = (unsigned char)(b & 0xFF);
            }
    if (bi != bj) {
#pragma unroll
        for (int mi = 0; mi < 4; ++mi)
#pragma unroll
            for (int ni = 0; ni < 4; ++ni) {
                int rowm = col0 + wcol + ni * 16 + mrow;
                int colm = row0 + wrow + mi * 16 + quad * 4;   // 4-aligned
                int pk = __builtin_amdgcn_cvt_pk_fp8_f32(
                             acc[mi][ni][0], acc[mi][ni][1], 0, false);
                pk = __builtin_amdgcn_cvt_pk_fp8_f32(
                         acc[mi][ni][2], acc[mi][ni][3], pk, true);
                *(int*)&outp[(size_t)rowm * BSZ + colm] = pk;
            }
    }
}

// K3: per-row loss, single pass. Scores <= 10 analytically (cosine/T), so use
// constant shift 10 (loss is shift-invariant); no srow LDS staging.
__global__ __launch_bounds__(256) void k_loss_rows(
    const unsigned char* __restrict__ partials, const float* __restrict__ inv_norm,
    const int* __restrict__ labels, float* __restrict__ rloss,
    float* __restrict__ rvalid, float* __restrict__ rcorr) {
    int i = blockIdx.x, tid = threadIdx.x;
    __shared__ float red[4];
    float inv_i = inv_norm[i];
    int lab_i = labels[i];

    int j4 = tid * 4;
    float sx = 0.f, sy = 0.f, sz = 0.f, sw = 0.f;
#pragma unroll
    for (int p2 = 0; p2 < SPLITK; ++p2) {
        int v = *(const int*)&partials[(size_t)p2 * BSZ * BSZ + (size_t)i * BSZ + j4];
        sx += __builtin_amdgcn_cvt_f32_fp8(v, 0);
        sy += __builtin_amdgcn_cvt_f32_fp8(v, 1);
        sz += __builtin_amdgcn_cvt_f32_fp8(v, 2);
        sw += __builtin_amdgcn_cvt_f32_fp8(v, 3);
    }
    float4 invj = *(const float4*)&inv_norm[j4];
    float s4[4];
    s4[0] = sx * inv_i * invj.x * TEMP_INV;
    s4[1] = sy * inv_i * invj.y * TEMP_INV;
    s4[2] = sz * inv_i * invj.z * TEMP_INV;
    s4[3] = sw * inv_i * invj.w * TEMP_INV;
    int4 labj = *(const int4*)&labels[j4];
    const int* labjp = &labj.x;

    float pos_sum = 0.f, neg_sum = 0.f, mp = -3.0e38f, mn = -3.0e38f;
#pragma unroll
    for (int q = 0; q < 4; ++q) {
        int j = j4 + q;
        if (j == i) continue;
        float s = s4[q];
        float e = __expf(s - 10.0f);           // s <= 10+eps -> e in (0,~1]
        if (labjp[q] == lab_i) { pos_sum += e; mp = fmaxf(mp, s); }
        else                   { neg_sum += e; mn = fmaxf(mn, s); }
    }
    float ps = blockSum(pos_sum, red, tid);
    float ns = blockSum(neg_sum, red, tid);
    float mpa = blockMax(mp, red, tid);
    float mna = blockMax(mn, red, tid);
    if (tid == 0) {
        bool valid = (mpa > -1.0e37f) && (mna > -1.0e37f);
        rloss[i]  = valid ? (logf(ns) - logf(ps)) : 0.f;
        rvalid[i] = valid ? 1.f : 0.f;
        rcorr[i]  = (valid && (mpa > mna)) ? 1.f : 0.f;
    }
}

// K4: final scalar reduce -> d_out[0]=loss, d_out[1]=accuracy
__global__ __launch_bounds__(256) void k_final(
    const float* __restrict__ rloss, const float* __restrict__ rvalid,
    const float* __restrict__ rcorr, float* __restrict__ out) {
    __shared__ float red[4];
    int tid = threadIdx.x;
    float sl = 0.f, sv = 0.f, sc = 0.f;
    for (int c = 0; c < 4; ++c) {
        int j = c * 256 + tid;
        sl += rloss[j]; sv += rvalid[j]; sc += rcorr[j];
    }
    sl = blockSum(sl, red, tid);
    sv = blockSum(sv, red, tid);
    sc = blockSum(sc, red, tid);
    if (tid == 0) {
        out[0] = (sv > 0.f) ? sl / fmaxf(sv, 1.f) : 0.f;
        out[1] = (sv > 0.f) ? sc / fmaxf(sv, 1.f) : 0.5f;
    }
}

extern "C" void kernel_launch(void* const* d_in, const int* in_sizes, int n_in,
                              void* d_out, int out_size, void* d_ws, size_t ws_size,
                              hipStream_t stream) {
    const float* feats = (const float*)d_in[0];
    const int* labels = (const int*)d_in[1];
    float* out = (float*)d_out;
    char* ws = (char*)d_ws;

    // ws: [0,32MB) fp8 features | [32MB,48MB) 16 fp8 gram partials | small arrays
    unsigned char* f8       = (unsigned char*)ws;
    unsigned char* partials = (unsigned char*)(ws + (size_t)32 * 1024 * 1024);
    float* inv_norm         = (float*)(ws + (size_t)64 * 1024 * 1024);
    float* rloss            = inv_norm + BSZ;
    float* rvalid           = rloss + BSZ;
    float* rcorr            = rvalid + BSZ;

    k_norm_convert<<<BSZ, 256, 0, stream>>>(feats, f8, inv_norm);
    k_gemm<<<dim3(36 * SPLITK), 256, 0, stream>>>(f8, partials);
    k_loss_rows<<<BSZ, 256, 0, stream>>>(partials, inv_norm, labels, rloss, rvalid, rcorr);
    k_final<<<1, 256, 0, stream>>>(rloss, rvalid, rcorr, out);
}